// Round 9
// baseline (74.556 us; speedup 1.0000x reference)
//
#include <hip/hip_runtime.h>
#include <hip/hip_bf16.h>

#define N_B   4
#define T_LEN 1024
#define NREF  128
#define H     4
#define KQ    128
#define LD    128
#define HKQ   512
#define HLD   512

typedef __attribute__((ext_vector_type(8))) short bf16x8;   // 8 bf16 = 4 VGPRs
typedef __attribute__((ext_vector_type(4))) float f32x4;

union V8 { __hip_bfloat16 h[8]; bf16x8 v; };

#define MFMA(a, b, c) __builtin_amdgcn_mfma_f32_16x16x32_bf16((a), (b), (c), 0, 0, 0)

__device__ __forceinline__ void sincos_pair(float t, int i, float* s, float* c) {
    // freq i in [0,32): angle = 48*t*exp(-2i*ln(10)/64)
    float div = __expf(-(float)(2 * i) * (2.302585093f / 64.0f));
    __sincosf(48.0f * t * div, s, c);
}

// generic k_in/q_in 8-col group (used for the one-shot qin build)
__device__ __forceinline__ bf16x8 kin_group(float t, int y0, int y1,
                                            const float* __restrict__ emb0,
                                            const float* __restrict__ emb1, int c0) {
    V8 v;
    if (c0 < 64) {
        #pragma unroll
        for (int jj = 0; jj < 8; jj += 2) {
            float s, c;
            sincos_pair(t, (c0 + jj) >> 1, &s, &c);
            v.h[jj] = __float2bfloat16(s);
            v.h[jj + 1] = __float2bfloat16(c);
        }
    } else if (c0 < 96) {
        const float* p = emb0 + y0 * 32 + (c0 - 64);
        #pragma unroll
        for (int jj = 0; jj < 8; ++jj) v.h[jj] = __float2bfloat16(p[jj]);
    } else {
        const float* p = emb1 + y1 * 32 + (c0 - 96);
        #pragma unroll
        for (int jj = 0; jj < 8; ++jj) v.h[jj] = __float2bfloat16(p[jj]);
    }
    return v.v;
}

// ONE kernel, ONE plain launch, NO grid sync. grid 128 = (qt 8, h 4, b 4), block 512 (8 waves).
// Per block: recompute A-tile (2 MFMA stages from Wq/Wk in LDS), build kin per-wave in LDS
// slots, exact two-pass softmax (one cross-wave LDS reduction), PV with per-chunk x
// transpose into wave-private LDS, partial projection vs LDS-staged WoT_h, then
// last-block-per-(qt,b) reduction of the 4 head partials (+bo) into out.
__global__ __launch_bounds__(512) void mono_kernel(
    const float* __restrict__ ts, const int* __restrict__ ys0, const int* __restrict__ ys1,
    const float* __restrict__ x,
    const float* __restrict__ emb0, const float* __restrict__ emb1,
    const float* __restrict__ Wq, const float* __restrict__ bq,
    const float* __restrict__ Wk, const float* __restrict__ Wo,
    const float* __restrict__ bo,
    float* pout, unsigned int* counter, float* out)
{
    // LDS: wlds 32K (WqT -> Wk_h -> P[16x1024] -> WoT_h), S 4K (qin -> hq -> A -> att),
    // slots 32K (8 waves x 4KB: kin subtile -> x subtile), reductions.
    __shared__ __align__(16) unsigned char wlds_raw[32768];
    __shared__ __align__(16) __hip_bfloat16 S[2048];
    __shared__ __align__(16) unsigned char slots_raw[32768];
    __shared__ float redm[128], reds[128];
    __shared__ int flagv;

    __hip_bfloat16* wlds = (__hip_bfloat16*)wlds_raw;

    int tid = threadIdx.x;
    int w = tid >> 6, lane = tid & 63;
    int lm = lane & 15, lg = lane >> 4;
    int blk = blockIdx.x;
    int qt = blk & 7, h = (blk >> 3) & 3, b = blk >> 5;
    int q0 = qt * 16;
    const float scale = 0.08838834764831845f;  // 1/sqrt(128)

    // ---------- build qin (16 rows q0..q0+15) into S (swizzled bf16) ----------
    if (tid < 256) {
        int row = tid >> 4, c0 = (tid & 15) * 8;
        float t = (float)(q0 + row) / 127.0f;   // linspace(0,1,128)
        bf16x8 g = kin_group(t, 100, 50, emb0, emb1, c0);
        *(bf16x8*)&S[(row * 128 + c0) ^ ((row & 7) << 3)] = g;
    }
    // ---------- stage WqT[d][i] (transpose of Wq_h) into wlds ----------
    for (int u = 0; u < 8; ++u) {
        int s = u * 512 + tid;          // 0..4095
        int i = s >> 5, d0 = (s & 31) * 4;
        float4 wv = *(const float4*)&Wq[(size_t)i * HKQ + h * KQ + d0];
        float arr[4] = {wv.x, wv.y, wv.z, wv.w};
        #pragma unroll
        for (int jj = 0; jj < 4; ++jj) {
            int d = d0 + jj;
            wlds[(d * 128 + i) ^ ((d & 7) << 3)] = __float2bfloat16(arr[jj]);
        }
    }
    __syncthreads();

    // ---------- A stage 1: hq[16x128] = qin @ WqT; wave w -> d-tile w ----------
    f32x4 hacc = f32x4{0.f, 0.f, 0.f, 0.f};
    #pragma unroll
    for (int ks = 0; ks < 4; ++ks) {
        bf16x8 a = *(bf16x8*)&S[(lm * 128 + ks * 32 + lg * 8) ^ ((lm & 7) << 3)];
        int d = w * 16 + lm;
        bf16x8 bb = *(bf16x8*)&wlds[(d * 128 + ks * 32 + lg * 8) ^ ((d & 7) << 3)];
        hacc = MFMA(a, bb, hacc);
    }
    __syncthreads();   // qin + WqT consumed
    {   // hq (+bq) -> S
        int d = w * 16 + lm;
        float bia = bq[h * KQ + d];
        #pragma unroll
        for (int r = 0; r < 4; ++r) {
            int q = 4 * lg + r;
            S[(q * 128 + d) ^ ((q & 7) << 3)] = __float2bfloat16(hacc[r] + bia);
        }
    }
    // stage Wk_h row-major into wlds
    for (int u = 0; u < 8; ++u) {
        int s = u * 512 + tid;
        int i = s >> 5, d0 = (s & 31) * 4;
        float4 wv = *(const float4*)&Wk[(size_t)i * HKQ + h * KQ + d0];
        __hip_bfloat16 hb[4] = {__float2bfloat16(wv.x), __float2bfloat16(wv.y),
                                __float2bfloat16(wv.z), __float2bfloat16(wv.w)};
        *(ushort4*)&wlds[(i * 128 + d0) ^ ((i & 7) << 3)] = *(ushort4*)hb;
    }
    __syncthreads();

    // ---------- A stage 2: A[16x128] = hq @ Wk_h^T; wave w -> i-tile w ----------
    f32x4 aacc = f32x4{0.f, 0.f, 0.f, 0.f};
    #pragma unroll
    for (int ks = 0; ks < 4; ++ks) {
        bf16x8 a = *(bf16x8*)&S[(lm * 128 + ks * 32 + lg * 8) ^ ((lm & 7) << 3)];
        int i2 = w * 16 + lm;
        bf16x8 bb = *(bf16x8*)&wlds[(i2 * 128 + ks * 32 + lg * 8) ^ ((i2 & 7) << 3)];
        aacc = MFMA(a, bb, aacc);
    }
    __syncthreads();   // hq consumed
    #pragma unroll
    for (int r = 0; r < 4; ++r) {
        int q = 4 * lg + r;
        int i2 = w * 16 + lm;
        S[(q * 128 + i2) ^ ((q & 7) << 3)] = __float2bfloat16(aacc[r]);
    }
    __syncthreads();   // A-tile ready

    // A-frags into registers (S gets reused later for att)
    bf16x8 af[4];
    #pragma unroll
    for (int ks = 0; ks < 4; ++ks)
        af[ks] = *(bf16x8*)&S[(lm * 128 + ks * 32 + lg * 8) ^ ((lm & 7) << 3)];

    // ---------- scores: wave w owns keys [w*128, w*128+128), 8 subchunks of 16 ----------
    __hip_bfloat16* slot = (__hip_bfloat16*)slots_raw + w * 2048;   // 4 KB private
    // per-lane hoisted frequency table (col group fixed per lane)
    int c0l = (lane & 15) * 8;
    float dv48[4];
    if (c0l < 64) {
        #pragma unroll
        for (int k = 0; k < 4; ++k)
            dv48[k] = 48.0f * __expf(-(float)(c0l + 2 * k) * (2.302585093f / 64.0f));
    }
    f32x4 sacc[8];
    #pragma unroll
    for (int s = 0; s < 8; ++s) sacc[s] = f32x4{0.f, 0.f, 0.f, 0.f};

    for (int s = 0; s < 8; ++s) {
        // build kin subtile: 16 rows (keys w*128 + s*16 + row), lane -> rows {lg,4+lg,8+lg,12+lg}
        #pragma unroll
        for (int u = 0; u < 4; ++u) {
            int row = u * 4 + lg;
            int bt = b * T_LEN + w * 128 + s * 16 + row;
            V8 v;
            if (c0l < 64) {
                float t = ts[bt];
                #pragma unroll
                for (int k = 0; k < 4; ++k) {
                    float sn, cs;
                    __sincosf(t * dv48[k], &sn, &cs);
                    v.h[2 * k] = __float2bfloat16(sn);
                    v.h[2 * k + 1] = __float2bfloat16(cs);
                }
            } else if (c0l < 96) {
                const float* p = emb0 + ys0[bt] * 32 + (c0l - 64);
                #pragma unroll
                for (int jj = 0; jj < 8; ++jj) v.h[jj] = __float2bfloat16(p[jj]);
            } else {
                const float* p = emb1 + ys1[bt] * 32 + (c0l - 96);
                #pragma unroll
                for (int jj = 0; jj < 8; ++jj) v.h[jj] = __float2bfloat16(p[jj]);
            }
            *(bf16x8*)&slot[(row * 128 + c0l) ^ ((row & 7) << 3)] = v.v;
        }
        // score this 16-key tile (compiler inserts lgkmcnt between wave's ds_write/ds_read)
        #pragma unroll
        for (int ks = 0; ks < 4; ++ks) {
            bf16x8 bb = *(bf16x8*)&slot[(lm * 128 + ks * 32 + lg * 8) ^ ((lm & 7) << 3)];
            sacc[s] = MFMA(af[ks], bb, sacc[s]);
        }
    }

    // ---------- exact two-pass softmax (one cross-wave reduction) ----------
    #pragma unroll
    for (int r = 0; r < 4; ++r) {
        float cm = sacc[0][r];
        #pragma unroll
        for (int s = 1; s < 8; ++s) cm = fmaxf(cm, sacc[s][r]);
        #pragma unroll
        for (int o = 8; o >= 1; o >>= 1) cm = fmaxf(cm, __shfl_xor(cm, o));
        if (lm == 0) redm[w * 16 + 4 * lg + r] = cm;
    }
    __syncthreads();   // redm ready; Wk reads in wlds long done -> P may overwrite
    #pragma unroll
    for (int r = 0; r < 4; ++r) {
        int q = 4 * lg + r;
        float cm = redm[q];
        #pragma unroll
        for (int ww = 1; ww < 8; ++ww) cm = fmaxf(cm, redm[ww * 16 + q]);
        float fm = cm * scale;
        float sum = 0.f;
        #pragma unroll
        for (int s = 0; s < 8; ++s) {
            float p = __expf(sacc[s][r] * scale - fm);
            sum += p;
            int key = w * 128 + s * 16 + lm;
            wlds[(q * 1024 + key) ^ ((q & 7) << 3)] = __float2bfloat16(p);   // P
        }
        #pragma unroll
        for (int o = 8; o >= 1; o >>= 1) sum += __shfl_xor(sum, o);
        if (lm == 0) reds[w * 16 + q] = sum;
    }
    __syncthreads();   // P + reds complete
    float l_[4];
    #pragma unroll
    for (int r = 0; r < 4; ++r) {
        int q = 4 * lg + r;
        float csum = reds[q];
        #pragma unroll
        for (int ww = 1; ww < 8; ++ww) csum += reds[ww * 16 + q];
        l_[r] = csum;
    }

    // ---------- PV: wave owns v = w*16+lm; 8 chunks of 128 t, x transposed per chunk ----------
    f32x4 oacc = f32x4{0.f, 0.f, 0.f, 0.f};
    for (int c = 0; c < 8; ++c) {
        int t0 = c * 128;
        #pragma unroll
        for (int p = 0; p < 8; ++p) {
            int tl = p * 16 + (lane >> 2);
            int v4 = (lane & 3) * 4;
            float4 xv = *(const float4*)&x[((size_t)(b * T_LEN + t0 + tl)) * LD + w * 16 + v4];
            float arr[4] = {xv.x, xv.y, xv.z, xv.w};
            #pragma unroll
            for (int jj = 0; jj < 4; ++jj) {
                int v = v4 + jj;
                slot[(v * 128 + tl) ^ ((v & 7) << 3)] = __float2bfloat16(arr[jj]);
            }
        }
        #pragma unroll
        for (int ks = 0; ks < 4; ++ks) {
            bf16x8 pa = *(bf16x8*)&wlds[(lm * 1024 + t0 + ks * 32 + lg * 8) ^ ((lm & 7) << 3)];
            bf16x8 xb = *(bf16x8*)&slot[(lm * 128 + ks * 32 + lg * 8) ^ ((lm & 7) << 3)];
            oacc = MFMA(pa, xb, oacc);
        }
    }
    // normalize -> att in S
    #pragma unroll
    for (int r = 0; r < 4; ++r) {
        int q = 4 * lg + r;
        S[(q * 128 + w * 16 + lm) ^ ((q & 7) << 3)] = __float2bfloat16(oacc[r] / l_[r]);
    }
    __syncthreads();   // att complete; P dead

    // ---------- stage WoT_h[j][i] (transpose of Wo rows h*128..) into wlds ----------
    for (int u = 0; u < 8; ++u) {
        int s = u * 512 + tid;          // 0..4095
        int il = s >> 5, j0 = (s & 31) * 4;
        float4 wv = *(const float4*)&Wo[((size_t)(h * KQ + il)) * LD + j0];
        float arr[4] = {wv.x, wv.y, wv.z, wv.w};
        #pragma unroll
        for (int jj = 0; jj < 4; ++jj) {
            int j = j0 + jj;
            wlds[(j * 128 + il) ^ ((j & 7) << 3)] = __float2bfloat16(arr[jj]);
        }
    }
    __syncthreads();

    // ---------- partial projection: wave w -> j-tile w ----------
    f32x4 cacc = f32x4{0.f, 0.f, 0.f, 0.f};
    #pragma unroll
    for (int ks = 0; ks < 4; ++ks) {
        bf16x8 aa = *(bf16x8*)&S[(lm * 128 + ks * 32 + lg * 8) ^ ((lm & 7) << 3)];
        int j = w * 16 + lm;
        bf16x8 wb = *(bf16x8*)&wlds[(j * 128 + ks * 32 + lg * 8) ^ ((j & 7) << 3)];
        cacc = MFMA(aa, wb, cacc);
    }
    // write partial to ws
    int grp = b * 8 + qt;
    float* pbase = pout + ((size_t)grp * 4 + h) * 2048;
    #pragma unroll
    for (int r = 0; r < 4; ++r) {
        int q = 4 * lg + r;
        pbase[q * 128 + w * 16 + lm] = cacc[r];
    }
    __threadfence();       // release: partials visible device-wide
    __syncthreads();       // all threads' stores+fences done before the atomic
    if (tid == 0) {
        unsigned int old = atomicAdd(&counter[grp], 1u);
        flagv = ((old & 3u) == 3u) ? 1 : 0;   // exactly one of any 4 consecutive values
    }
    __syncthreads();
    if (flagv) {
        __threadfence();   // acquire: other blocks' released partials visible
        const float* p0 = pout + (size_t)grp * 4 * 2048;
        for (int e = tid; e < 2048; e += 512) {
            int q = e >> 7, j = e & 127;
            float v = bo[j] + p0[e] + p0[2048 + e] + p0[2 * 2048 + e] + p0[3 * 2048 + e];
            out[((size_t)(b * NREF + q0 + q)) * LD + j] = v;
        }
    }
}

extern "C" void kernel_launch(void* const* d_in, const int* in_sizes, int n_in,
                              void* d_out, int out_size, void* d_ws, size_t ws_size,
                              hipStream_t stream) {
    const float* ts   = (const float*)d_in[0];
    const int*   ys0  = (const int*)d_in[1];
    const int*   ys1  = (const int*)d_in[2];
    const float* x    = (const float*)d_in[3];
    const float* emb0 = (const float*)d_in[4];
    const float* emb1 = (const float*)d_in[5];
    const float* Wq   = (const float*)d_in[6];
    const float* bq   = (const float*)d_in[7];
    const float* Wk   = (const float*)d_in[8];
    // d_in[9] = bk: cancels exactly in softmax (constant per (h,q) row) — unused
    const float* Wo   = (const float*)d_in[10];
    const float* bo   = (const float*)d_in[11];
    float* out = (float*)d_out;

    unsigned int* counter = (unsigned int*)d_ws;            // 32 counters (mod-4 logic:
                                                            // any start value works, incl 0xAA poison)
    float* pout = (float*)((char*)d_ws + 512);              // 32 groups * 4 heads * 2048 f32 = 1 MB

    hipLaunchKernelGGL(mono_kernel, dim3(128), dim3(512), 0, stream,
                       ts, ys0, ys1, x, emb0, emb1, Wq, bq, Wk, Wo, bo,
                       pout, counter, out);
}